// Round 3
// baseline (919.400 us; speedup 1.0000x reference)
//
#include <hip/hip_runtime.h>
#include <math.h>

// ---------------- device helpers ----------------
__device__ __forceinline__ int dev_lower_bound(const int* __restrict__ a, int n, int v){
  int lo = 0, hi = n;
  while (lo < hi){ int mid = (lo + hi) >> 1; if (a[mid] < v) lo = mid + 1; else hi = mid; }
  return lo;
}

// ---------------- CSR build ----------------
// deg[] zeroed via hipMemsetAsync before this; counts real edges only.
__global__ __launch_bounds__(256) void hist_kernel(const int* __restrict__ edst,
                                                   int* __restrict__ deg, int nE){
  int t = blockIdx.x * blockDim.x + threadIdx.x;
  int i = t * 4;
  int stride = gridDim.x * blockDim.x * 4;
  for (; i + 3 < nE; i += stride){
    int4 d = *(const int4*)(edst + i);
    atomicAdd(&deg[d.x], 1); atomicAdd(&deg[d.y], 1);
    atomicAdd(&deg[d.z], 1); atomicAdd(&deg[d.w], 1);
  }
  for (; i < nE; ++i) atomicAdd(&deg[edst[i]], 1);
}

// Prefix sum over (deg[i]+1); also places each node's self-loop at the END of
// its row (csr_src[row_off[i]+deg[i]] = i) so scatter never touches it.
__global__ __launch_bounds__(1024) void scan_kernel(const int* __restrict__ deg,
    int* __restrict__ row_off, int* __restrict__ cursor, int* __restrict__ csr_src, int n){
  __shared__ int sums[1024];
  int tid = threadIdx.x;
  int chunk = (n + 1023) >> 10;
  int beg = tid * chunk;
  int end = min(beg + chunk, n);
  int s = 0;
  for (int i = beg; i < end; ++i) s += deg[i] + 1;
  sums[tid] = s;
  __syncthreads();
  for (int off = 1; off < 1024; off <<= 1){
    int v = (tid >= off) ? sums[tid - off] : 0;
    __syncthreads();
    sums[tid] += v;
    __syncthreads();
  }
  int run = (tid == 0) ? 0 : sums[tid - 1];
  for (int i = beg; i < end; ++i){
    int d = deg[i];
    row_off[i] = run;
    cursor[i]  = run;
    csr_src[run + d] = i;          // self-loop slot
    run += d + 1;
  }
  if (tid == 0) row_off[n] = sums[1023];
}

// ---------------- shared gemm body: out = X @ W + b  (tile 128x128, K=128) ----
__device__ __forceinline__ void gemm_body(
    const float* __restrict__ X, const float* __restrict__ W,
    const float* __restrict__ b, float* __restrict__ out, int n, int bx,
    float (*Ws)[128], float (*Xs)[36])
{
  const int tid = threadIdx.x;
  const int row0 = bx * 128;
  const int tc = tid & 31;           // 4 output cols
  const int tr = tid >> 5;           // 8 rows
  float acc[8][4] = {};
  for (int kc = 0; kc < 128; kc += 32){
    for (int idx = tid; idx < 1024; idx += 512){          // W chunk: 32x128
      int r = idx >> 5, c4 = idx & 31;
      *(float4*)(&Ws[r][c4 * 4]) = *(const float4*)(W + (size_t)(kc + r) * 128 + c4 * 4);
    }
    for (int idx = tid; idx < 1024; idx += 512){          // X chunk: 128x32
      int r = idx >> 3, c4 = idx & 7;
      int grow = row0 + r;
      float4 v = make_float4(0.f, 0.f, 0.f, 0.f);
      if (grow < n) v = *(const float4*)(X + (size_t)grow * 128 + kc + c4 * 4);
      *(float4*)(&Xs[r][c4 * 4]) = v;
    }
    __syncthreads();
    #pragma unroll
    for (int k = 0; k < 32; ++k){
      float4 w = *(const float4*)(&Ws[k][tc * 4]);
      #pragma unroll
      for (int r = 0; r < 8; ++r){
        float xv = Xs[tr * 8 + r][k];
        acc[r][0] = fmaf(xv, w.x, acc[r][0]);
        acc[r][1] = fmaf(xv, w.y, acc[r][1]);
        acc[r][2] = fmaf(xv, w.z, acc[r][2]);
        acc[r][3] = fmaf(xv, w.w, acc[r][3]);
      }
    }
    __syncthreads();
  }
  float4 bv = *(const float4*)(b + tc * 4);
  #pragma unroll
  for (int r = 0; r < 8; ++r){
    int grow = row0 + tr * 8 + r;
    if (grow < n){
      float4 o = make_float4(acc[r][0] + bv.x, acc[r][1] + bv.y,
                             acc[r][2] + bv.z, acc[r][3] + bv.w);
      *(float4*)(out + (size_t)grow * 128 + tc * 4) = o;
    }
  }
}

// standalone gemm (layers 2,3): grid (tiles, 2)
__global__ __launch_bounds__(512) void gemm_xlxr_kernel(
    const float* __restrict__ X,
    const float* __restrict__ Wl, const float* __restrict__ bl,
    const float* __restrict__ Wr, const float* __restrict__ br,
    float* __restrict__ xl, float* __restrict__ xr, int n)
{
  __shared__ float Ws[32][128];
  __shared__ float Xs[128][36];
  if (blockIdx.y == 0) gemm_body(X, Wl, bl, xl, n, blockIdx.x, Ws, Xs);
  else                 gemm_body(X, Wr, br, xr, n, blockIdx.x, Ws, Xs);
}

// fused: layer-1 gemm (blocks [0,gemm_blocks)) + edge scatter (the rest).
// Independent work co-scheduled so scatter's atomic latency hides under gemm.
__global__ __launch_bounds__(512) void gemm_scatter_kernel(
    const float* __restrict__ X,
    const float* __restrict__ Wl, const float* __restrict__ bl,
    const float* __restrict__ Wr, const float* __restrict__ br,
    float* __restrict__ xl, float* __restrict__ xr, int n, int gemm_blocks,
    const int* __restrict__ esrc, const int* __restrict__ edst,
    int* __restrict__ cursor, int* __restrict__ csr_src, int nE)
{
  __shared__ float Ws[32][128];
  __shared__ float Xs[128][36];
  if ((int)blockIdx.x < gemm_blocks){
    const int bx = blockIdx.x >> 1;
    if ((blockIdx.x & 1) == 0) gemm_body(X, Wl, bl, xl, n, bx, Ws, Xs);
    else                       gemm_body(X, Wr, br, xr, n, bx, Ws, Xs);
  } else {
    const int sb = blockIdx.x - gemm_blocks;
    int t = sb * blockDim.x + threadIdx.x;
    int i = t * 4;
    int stride = (gridDim.x - gemm_blocks) * blockDim.x * 4;
    for (; i + 3 < nE; i += stride){
      int4 s4 = *(const int4*)(esrc + i);
      int4 d4 = *(const int4*)(edst + i);
      int p0 = atomicAdd(&cursor[d4.x], 1);
      int p1 = atomicAdd(&cursor[d4.y], 1);
      int p2 = atomicAdd(&cursor[d4.z], 1);
      int p3 = atomicAdd(&cursor[d4.w], 1);
      csr_src[p0] = s4.x; csr_src[p1] = s4.y;
      csr_src[p2] = s4.z; csr_src[p3] = s4.w;
    }
    for (; i < nE; ++i){
      int p = atomicAdd(&cursor[edst[i]], 1);
      csr_src[p] = esrc[i];
    }
  }
}

// ---------------- per-destination online-softmax attention ----------------
// ONE 64-lane wave per destination node. Each 32-lane half owns all 128
// feature cols (float4/lane) and processes alternating edge PAIRS; the two
// half-states are merged flash-style at the end. Branchless tail via
// clamped indices + predicated-zero exp weights.
__global__ __launch_bounds__(256) void edge_attn_kernel(
    const float* __restrict__ xl, const float* __restrict__ xr,
    const int* __restrict__ row_off, const int* __restrict__ csr_src,
    const float* __restrict__ att, const float* __restrict__ bias,
    float* __restrict__ out, int n, int do_relu)
{
  const int node = (blockIdx.x * blockDim.x + threadIdx.x) >> 6;
  if (node >= n) return;
  const int lane = threadIdx.x & 63;
  const int half = lane >> 5;
  const int f4 = (lane & 31) * 4;

  const float4 xrv  = *(const float4*)(xr + (size_t)node * 128 + f4);
  const float4 attv = *(const float4*)(att + f4);
  const int base = row_off[node];
  const int deg  = row_off[node + 1] - base;       // >= 1 (self-loop)
  const int iters = (deg + 3) >> 2;

  float m = -3.0e38f, s = 0.f;
  float ax = 0.f, ay = 0.f, az = 0.f, aw = 0.f;

  for (int it = 0; it < iters; ++it){
    const int e0 = it * 4 + half * 2;
    const int e1 = e0 + 1;
    const int c0 = min(e0, deg - 1);
    const int c1 = min(e1, deg - 1);
    const int s0 = csr_src[base + c0];
    const int s1 = csr_src[base + c1];
    const float4 x0 = *(const float4*)(xl + (size_t)s0 * 128 + f4);
    const float4 x1 = *(const float4*)(xl + (size_t)s1 * 128 + f4);

    float t, p0, p1;
    t = x0.x + xrv.x; t = fmaxf(t, 0.2f * t); p0 = t * attv.x;
    t = x0.y + xrv.y; t = fmaxf(t, 0.2f * t); p0 = fmaf(t, attv.y, p0);
    t = x0.z + xrv.z; t = fmaxf(t, 0.2f * t); p0 = fmaf(t, attv.z, p0);
    t = x0.w + xrv.w; t = fmaxf(t, 0.2f * t); p0 = fmaf(t, attv.w, p0);
    t = x1.x + xrv.x; t = fmaxf(t, 0.2f * t); p1 = t * attv.x;
    t = x1.y + xrv.y; t = fmaxf(t, 0.2f * t); p1 = fmaf(t, attv.y, p1);
    t = x1.z + xrv.z; t = fmaxf(t, 0.2f * t); p1 = fmaf(t, attv.z, p1);
    t = x1.w + xrv.w; t = fmaxf(t, 0.2f * t); p1 = fmaf(t, attv.w, p1);
    #pragma unroll
    for (int off = 1; off < 32; off <<= 1){       // per-half reduction
      p0 += __shfl_xor(p0, off);
      p1 += __shfl_xor(p1, off);
    }
    // batched online-softmax update (one rescale per 2 edges)
    float mnew = fmaxf(fmaxf(m, p0), p1);         // duplicates can't exceed max
    float sc = __expf(m - mnew);                  // first iter: exp(-3e38)=0
    float q0 = __expf(p0 - mnew);
    float q1 = __expf(p1 - mnew);
    q0 = (e0 < deg) ? q0 : 0.f;                   // kill clamped duplicates
    q1 = (e1 < deg) ? q1 : 0.f;
    s  = fmaf(s, sc, q0 + q1);
    ax = fmaf(ax, sc, fmaf(q0, x0.x, q1 * x1.x));
    ay = fmaf(ay, sc, fmaf(q0, x0.y, q1 * x1.y));
    az = fmaf(az, sc, fmaf(q0, x0.z, q1 * x1.z));
    aw = fmaf(aw, sc, fmaf(q0, x0.w, q1 * x1.w));
    m = mnew;
  }

  // merge the two half-states (flash merge across lane^32)
  float mo = __shfl_xor(m, 32);
  float mm = fmaxf(m, mo);
  float sc = __expf(m - mm);                      // empty half: exp(-3e38)=0
  s *= sc; ax *= sc; ay *= sc; az *= sc; aw *= sc;
  s  += __shfl_xor(s , 32);
  ax += __shfl_xor(ax, 32);
  ay += __shfl_xor(ay, 32);
  az += __shfl_xor(az, 32);
  aw += __shfl_xor(aw, 32);

  if (half == 0){
    const float inv = 1.0f / s;
    const float4 bv = *(const float4*)(bias + f4);
    float ox = fmaf(ax, inv, bv.x);
    float oy = fmaf(ay, inv, bv.y);
    float oz = fmaf(az, inv, bv.z);
    float ow = fmaf(aw, inv, bv.w);
    if (do_relu){
      ox = fmaxf(ox, 0.f); oy = fmaxf(oy, 0.f);
      oz = fmaxf(oz, 0.f); ow = fmaxf(ow, 0.f);
    }
    *(float4*)(out + (size_t)node * 128 + f4) = make_float4(ox, oy, oz, ow);
  }
}

// ---------------- mean-pool + MLP head ----------------
__global__ __launch_bounds__(128) void pool_mlp_kernel(
    const float* __restrict__ h, const int* __restrict__ batch, int n,
    const float* __restrict__ W4, const float* __restrict__ b4,
    const float* __restrict__ W5, const float* __restrict__ b5,
    const float* __restrict__ W6, const float* __restrict__ b6,
    float* __restrict__ out)
{
  int g = blockIdx.x;
  int t = threadIdx.x;
  __shared__ float gf[128];
  __shared__ float h1[128];
  __shared__ float h2[64];
  int lo = dev_lower_bound(batch, n, g);
  int hi = dev_lower_bound(batch, n, g + 1);
  float ssum = 0.f;
  for (int i = lo; i < hi; ++i) ssum += h[(size_t)i * 128 + t];
  float cnt = (float)(hi - lo);
  gf[t] = ssum / fmaxf(cnt, 1.0f);
  __syncthreads();
  float a = b4[t];
  for (int k = 0; k < 128; ++k) a = fmaf(gf[k], W4[k * 128 + t], a);
  h1[t] = 1.0f / (1.0f + __expf(-a));
  __syncthreads();
  if (t < 64){
    float a5 = b5[t];
    for (int k = 0; k < 128; ++k) a5 = fmaf(h1[k], W5[k * 64 + t], a5);
    h2[t] = 1.0f / (1.0f + __expf(-a5));
  }
  __syncthreads();
  if (t < 2){
    float a6 = b6[t];
    for (int k = 0; k < 64; ++k) a6 = fmaf(h2[k], W6[k * 2 + t], a6);
    out[g * 2 + t] = a6;
  }
}

// ---------------- launcher ----------------
extern "C" void kernel_launch(void* const* d_in, const int* in_sizes, int n_in,
                              void* d_out, int out_size, void* d_ws, size_t ws_size,
                              hipStream_t stream)
{
  const float* x          = (const float*)d_in[0];
  const int*   edge_index = (const int*)d_in[1];
  const int*   batch      = (const int*)d_in[2];
  const int n  = in_sizes[0] / 128;            // 50000
  const int nE = in_sizes[1] / 2;              // 1600000
  const int* esrc = edge_index;
  const int* edst = edge_index + nE;
  const int n_graphs = out_size / 2;           // 512

  const float *Wl[3], *bl[3], *Wr[3], *br[3], *att[3], *bias[3];
  for (int l = 0; l < 3; ++l){
    Wl[l]   = (const float*)d_in[3 + 6 * l + 0];
    bl[l]   = (const float*)d_in[3 + 6 * l + 1];
    Wr[l]   = (const float*)d_in[3 + 6 * l + 2];
    br[l]   = (const float*)d_in[3 + 6 * l + 3];
    att[l]  = (const float*)d_in[3 + 6 * l + 4];
    bias[l] = (const float*)d_in[3 + 6 * l + 5];
  }
  const float* W4 = (const float*)d_in[21]; const float* b4 = (const float*)d_in[22];
  const float* W5 = (const float*)d_in[23]; const float* b5 = (const float*)d_in[24];
  const float* W6 = (const float*)d_in[25]; const float* b6 = (const float*)d_in[26];

  char* ws = (char*)d_ws;
  size_t off = 0;
  auto alloc = [&](size_t bytes) -> void* {
    void* p = ws + off;
    off = (off + bytes + 255) & ~(size_t)255;
    return p;
  };
  int*   row_off = (int*)  alloc((size_t)(n + 1) * sizeof(int));
  int*   deg     = (int*)  alloc((size_t)n * sizeof(int));
  int*   cursor  = (int*)  alloc((size_t)n * sizeof(int));
  int*   csr_src = (int*)  alloc((size_t)(nE + n) * sizeof(int));
  float* xlb     = (float*)alloc((size_t)n * 128 * sizeof(float));
  float* xrb     = (float*)alloc((size_t)n * 128 * sizeof(float));
  float* hC      = (float*)alloc((size_t)n * 128 * sizeof(float));
  float* hD      = (float*)alloc((size_t)n * 128 * sizeof(float));
  (void)ws_size; (void)n_in;

  // CSR build
  hipMemsetAsync(deg, 0, (size_t)n * sizeof(int), stream);
  {
    int hb = (nE / 4 + 255) / 256;
    hist_kernel<<<hb, 256, 0, stream>>>(edst, deg, nE);
  }
  scan_kernel<<<1, 1024, 0, stream>>>(deg, row_off, cursor, csr_src, n);

  const int gemm_tiles = (n + 127) / 128;
  const int gemm_blocks = gemm_tiles * 2;
  const int scat_blocks = (nE + 4 * 512 - 1) / (4 * 512);
  const int attn_blocks = ((size_t)n * 64 + 255) / 256;

  // layer 1: fused gemm + scatter (independent work co-scheduled)
  gemm_scatter_kernel<<<gemm_blocks + scat_blocks, 512, 0, stream>>>(
      x, Wl[0], bl[0], Wr[0], br[0], xlb, xrb, n, gemm_blocks,
      esrc, edst, cursor, csr_src, nE);
  edge_attn_kernel<<<attn_blocks, 256, 0, stream>>>(xlb, xrb, row_off, csr_src,
                                                    att[0], bias[0], hC, n, 1);
  // layer 2
  gemm_xlxr_kernel<<<dim3(gemm_tiles, 2), 512, 0, stream>>>(hC, Wl[1], bl[1], Wr[1], br[1],
                                                            xlb, xrb, n);
  edge_attn_kernel<<<attn_blocks, 256, 0, stream>>>(xlb, xrb, row_off, csr_src,
                                                    att[1], bias[1], hD, n, 1);
  // layer 3
  gemm_xlxr_kernel<<<dim3(gemm_tiles, 2), 512, 0, stream>>>(hD, Wl[2], bl[2], Wr[2], br[2],
                                                            xlb, xrb, n);
  edge_attn_kernel<<<attn_blocks, 256, 0, stream>>>(xlb, xrb, row_off, csr_src,
                                                    att[2], bias[2], hC, n, 0);

  pool_mlp_kernel<<<n_graphs, 128, 0, stream>>>(hC, batch, n, W4, b4, W5, b5, W6, b6,
                                                (float*)d_out);
}

// Round 4
// 782.360 us; speedup vs baseline: 1.1752x; 1.1752x over previous
//
#include <hip/hip_runtime.h>
#include <hip/hip_bf16.h>
#include <math.h>

// ---------------- device helpers ----------------
__device__ __forceinline__ int dev_lower_bound(const int* __restrict__ a, int n, int v){
  int lo = 0, hi = n;
  while (lo < hi){ int mid = (lo + hi) >> 1; if (a[mid] < v) lo = mid + 1; else hi = mid; }
  return lo;
}

__device__ __forceinline__ float4 bf4_to_f4(ushort4 u){
  return make_float4(__uint_as_float((unsigned)u.x << 16),
                     __uint_as_float((unsigned)u.y << 16),
                     __uint_as_float((unsigned)u.z << 16),
                     __uint_as_float((unsigned)u.w << 16));
}

__device__ __forceinline__ unsigned short f_to_bf(float f){
  __hip_bfloat16 h = __float2bfloat16(f);      // RNE
  return *reinterpret_cast<unsigned short*>(&h);
}

// ---------------- CSR build ----------------
__global__ __launch_bounds__(256) void hist_kernel(const int* __restrict__ edst,
                                                   int* __restrict__ deg, int nE){
  int t = blockIdx.x * blockDim.x + threadIdx.x;
  int i = t * 8;
  if (i + 7 < nE){
    int4 a = *(const int4*)(edst + i);
    int4 b = *(const int4*)(edst + i + 4);
    atomicAdd(&deg[a.x], 1); atomicAdd(&deg[a.y], 1);
    atomicAdd(&deg[a.z], 1); atomicAdd(&deg[a.w], 1);
    atomicAdd(&deg[b.x], 1); atomicAdd(&deg[b.y], 1);
    atomicAdd(&deg[b.z], 1); atomicAdd(&deg[b.w], 1);
  } else {
    for (; i < nE; ++i) atomicAdd(&deg[edst[i]], 1);
  }
}

// Prefix sum over (deg[i]+1); self-loop placed at END of each row.
__global__ __launch_bounds__(1024) void scan_kernel(const int* __restrict__ deg,
    int* __restrict__ row_off, int* __restrict__ cursor, int* __restrict__ csr_src, int n){
  __shared__ int sums[1024];
  int tid = threadIdx.x;
  int chunk = (n + 1023) >> 10;
  int beg = tid * chunk;
  int end = min(beg + chunk, n);
  int s = 0;
  for (int i = beg; i < end; ++i) s += deg[i] + 1;
  sums[tid] = s;
  __syncthreads();
  for (int off = 1; off < 1024; off <<= 1){
    int v = (tid >= off) ? sums[tid - off] : 0;
    __syncthreads();
    sums[tid] += v;
    __syncthreads();
  }
  int run = (tid == 0) ? 0 : sums[tid - 1];
  for (int i = beg; i < end; ++i){
    int d = deg[i];
    row_off[i] = run;
    cursor[i]  = run;
    csr_src[run + d] = i;          // self-loop slot
    run += d + 1;
  }
  if (tid == 0) row_off[n] = sums[1023];
}

// standalone scatter: tiny VGPR footprint -> high occupancy, 8 chains/thread
__global__ __launch_bounds__(256) void scatter_kernel(const int* __restrict__ esrc,
    const int* __restrict__ edst, int* __restrict__ cursor,
    int* __restrict__ csr_src, int nE){
  int t = blockIdx.x * blockDim.x + threadIdx.x;
  int i = t * 8;
  if (i + 7 < nE){
    int4 s0 = *(const int4*)(esrc + i);
    int4 s1 = *(const int4*)(esrc + i + 4);
    int4 d0 = *(const int4*)(edst + i);
    int4 d1 = *(const int4*)(edst + i + 4);
    int p0 = atomicAdd(&cursor[d0.x], 1);
    int p1 = atomicAdd(&cursor[d0.y], 1);
    int p2 = atomicAdd(&cursor[d0.z], 1);
    int p3 = atomicAdd(&cursor[d0.w], 1);
    int p4 = atomicAdd(&cursor[d1.x], 1);
    int p5 = atomicAdd(&cursor[d1.y], 1);
    int p6 = atomicAdd(&cursor[d1.z], 1);
    int p7 = atomicAdd(&cursor[d1.w], 1);
    csr_src[p0] = s0.x; csr_src[p1] = s0.y; csr_src[p2] = s0.z; csr_src[p3] = s0.w;
    csr_src[p4] = s1.x; csr_src[p5] = s1.y; csr_src[p6] = s1.z; csr_src[p7] = s1.w;
  } else {
    for (; i < nE; ++i){
      int p = atomicAdd(&cursor[edst[i]], 1);
      csr_src[p] = esrc[i];
    }
  }
}

// ---------------- fused xl/xr GEMM: tile 128x128, K=128 ----------------
// blockIdx.y==0: xl = X@Wl+bl written as BF16 (consumed only by edge gather)
// blockIdx.y==1: xr = X@Wr+br written as FP32
__global__ __launch_bounds__(512) void gemm_xlxr_kernel(
    const float* __restrict__ X,
    const float* __restrict__ Wl, const float* __restrict__ bl,
    const float* __restrict__ Wr, const float* __restrict__ br,
    unsigned short* __restrict__ xl16, float* __restrict__ xr, int n)
{
  const bool left = (blockIdx.y == 0);
  const float* W = left ? Wl : Wr;
  const float* b = left ? bl : br;
  __shared__ float Ws[32][128];
  __shared__ float Xs[128][36];
  const int tid = threadIdx.x;
  const int row0 = blockIdx.x * 128;
  const int tc = tid & 31;
  const int tr = tid >> 5;
  float acc[8][4] = {};
  for (int kc = 0; kc < 128; kc += 32){
    for (int idx = tid; idx < 1024; idx += 512){
      int r = idx >> 5, c4 = idx & 31;
      *(float4*)(&Ws[r][c4 * 4]) = *(const float4*)(W + (size_t)(kc + r) * 128 + c4 * 4);
    }
    for (int idx = tid; idx < 1024; idx += 512){
      int r = idx >> 3, c4 = idx & 7;
      int grow = row0 + r;
      float4 v = make_float4(0.f, 0.f, 0.f, 0.f);
      if (grow < n) v = *(const float4*)(X + (size_t)grow * 128 + kc + c4 * 4);
      *(float4*)(&Xs[r][c4 * 4]) = v;
    }
    __syncthreads();
    #pragma unroll
    for (int k = 0; k < 32; ++k){
      float4 w = *(const float4*)(&Ws[k][tc * 4]);
      #pragma unroll
      for (int r = 0; r < 8; ++r){
        float xv = Xs[tr * 8 + r][k];
        acc[r][0] = fmaf(xv, w.x, acc[r][0]);
        acc[r][1] = fmaf(xv, w.y, acc[r][1]);
        acc[r][2] = fmaf(xv, w.z, acc[r][2]);
        acc[r][3] = fmaf(xv, w.w, acc[r][3]);
      }
    }
    __syncthreads();
  }
  float4 bv = *(const float4*)(b + tc * 4);
  #pragma unroll
  for (int r = 0; r < 8; ++r){
    int grow = row0 + tr * 8 + r;
    if (grow < n){
      float ox = acc[r][0] + bv.x, oy = acc[r][1] + bv.y;
      float oz = acc[r][2] + bv.z, ow = acc[r][3] + bv.w;
      if (left){
        ushort4 o;
        o.x = f_to_bf(ox); o.y = f_to_bf(oy); o.z = f_to_bf(oz); o.w = f_to_bf(ow);
        *(ushort4*)(xl16 + (size_t)grow * 128 + tc * 4) = o;
      } else {
        *(float4*)(xr + (size_t)grow * 128 + tc * 4) = make_float4(ox, oy, oz, ow);
      }
    }
  }
}

// ---------------- per-destination online-softmax attention ----------------
// ONE 64-lane wave per destination node; halves process alternating edge
// pairs; flash-style half merge at the end. xl gathered as BF16 (8B/lane).
__global__ __launch_bounds__(256) void edge_attn_kernel(
    const unsigned short* __restrict__ xl16, const float* __restrict__ xr,
    const int* __restrict__ row_off, const int* __restrict__ csr_src,
    const float* __restrict__ att, const float* __restrict__ bias,
    float* __restrict__ out, int n, int do_relu)
{
  const int node = (blockIdx.x * blockDim.x + threadIdx.x) >> 6;
  if (node >= n) return;
  const int lane = threadIdx.x & 63;
  const int half = lane >> 5;
  const int f4 = (lane & 31) * 4;

  const float4 xrv  = *(const float4*)(xr + (size_t)node * 128 + f4);
  const float4 attv = *(const float4*)(att + f4);
  const int base = row_off[node];
  const int deg  = row_off[node + 1] - base;       // >= 1 (self-loop)
  const int iters = (deg + 3) >> 2;

  float m = -3.0e38f, s = 0.f;
  float ax = 0.f, ay = 0.f, az = 0.f, aw = 0.f;

  for (int it = 0; it < iters; ++it){
    const int e0 = it * 4 + half * 2;
    const int e1 = e0 + 1;
    const int c0 = min(e0, deg - 1);
    const int c1 = min(e1, deg - 1);
    const int s0 = csr_src[base + c0];
    const int s1 = csr_src[base + c1];
    const float4 x0 = bf4_to_f4(*(const ushort4*)(xl16 + (size_t)s0 * 128 + f4));
    const float4 x1 = bf4_to_f4(*(const ushort4*)(xl16 + (size_t)s1 * 128 + f4));

    float t, p0, p1;
    t = x0.x + xrv.x; t = fmaxf(t, 0.2f * t); p0 = t * attv.x;
    t = x0.y + xrv.y; t = fmaxf(t, 0.2f * t); p0 = fmaf(t, attv.y, p0);
    t = x0.z + xrv.z; t = fmaxf(t, 0.2f * t); p0 = fmaf(t, attv.z, p0);
    t = x0.w + xrv.w; t = fmaxf(t, 0.2f * t); p0 = fmaf(t, attv.w, p0);
    t = x1.x + xrv.x; t = fmaxf(t, 0.2f * t); p1 = t * attv.x;
    t = x1.y + xrv.y; t = fmaxf(t, 0.2f * t); p1 = fmaf(t, attv.y, p1);
    t = x1.z + xrv.z; t = fmaxf(t, 0.2f * t); p1 = fmaf(t, attv.z, p1);
    t = x1.w + xrv.w; t = fmaxf(t, 0.2f * t); p1 = fmaf(t, attv.w, p1);
    #pragma unroll
    for (int off = 1; off < 32; off <<= 1){
      p0 += __shfl_xor(p0, off);
      p1 += __shfl_xor(p1, off);
    }
    float mnew = fmaxf(fmaxf(m, p0), p1);
    float sc = __expf(m - mnew);
    float q0 = __expf(p0 - mnew);
    float q1 = __expf(p1 - mnew);
    q0 = (e0 < deg) ? q0 : 0.f;
    q1 = (e1 < deg) ? q1 : 0.f;
    s  = fmaf(s, sc, q0 + q1);
    ax = fmaf(ax, sc, fmaf(q0, x0.x, q1 * x1.x));
    ay = fmaf(ay, sc, fmaf(q0, x0.y, q1 * x1.y));
    az = fmaf(az, sc, fmaf(q0, x0.z, q1 * x1.z));
    aw = fmaf(aw, sc, fmaf(q0, x0.w, q1 * x1.w));
    m = mnew;
  }

  // flash merge across lane^32
  float mo = __shfl_xor(m, 32);
  float mm = fmaxf(m, mo);
  float sc = __expf(m - mm);
  s *= sc; ax *= sc; ay *= sc; az *= sc; aw *= sc;
  s  += __shfl_xor(s , 32);
  ax += __shfl_xor(ax, 32);
  ay += __shfl_xor(ay, 32);
  az += __shfl_xor(az, 32);
  aw += __shfl_xor(aw, 32);

  if (half == 0){
    const float inv = 1.0f / s;
    const float4 bv = *(const float4*)(bias + f4);
    float ox = fmaf(ax, inv, bv.x);
    float oy = fmaf(ay, inv, bv.y);
    float oz = fmaf(az, inv, bv.z);
    float ow = fmaf(aw, inv, bv.w);
    if (do_relu){
      ox = fmaxf(ox, 0.f); oy = fmaxf(oy, 0.f);
      oz = fmaxf(oz, 0.f); ow = fmaxf(ow, 0.f);
    }
    *(float4*)(out + (size_t)node * 128 + f4) = make_float4(ox, oy, oz, ow);
  }
}

// ---------------- mean-pool + MLP head ----------------
__global__ __launch_bounds__(128) void pool_mlp_kernel(
    const float* __restrict__ h, const int* __restrict__ batch, int n,
    const float* __restrict__ W4, const float* __restrict__ b4,
    const float* __restrict__ W5, const float* __restrict__ b5,
    const float* __restrict__ W6, const float* __restrict__ b6,
    float* __restrict__ out)
{
  int g = blockIdx.x;
  int t = threadIdx.x;
  __shared__ float gf[128];
  __shared__ float h1[128];
  __shared__ float h2[64];
  int lo = dev_lower_bound(batch, n, g);
  int hi = dev_lower_bound(batch, n, g + 1);
  float ssum = 0.f;
  for (int i = lo; i < hi; ++i) ssum += h[(size_t)i * 128 + t];
  float cnt = (float)(hi - lo);
  gf[t] = ssum / fmaxf(cnt, 1.0f);
  __syncthreads();
  float a = b4[t];
  for (int k = 0; k < 128; ++k) a = fmaf(gf[k], W4[k * 128 + t], a);
  h1[t] = 1.0f / (1.0f + __expf(-a));
  __syncthreads();
  if (t < 64){
    float a5 = b5[t];
    for (int k = 0; k < 128; ++k) a5 = fmaf(h1[k], W5[k * 64 + t], a5);
    h2[t] = 1.0f / (1.0f + __expf(-a5));
  }
  __syncthreads();
  if (t < 2){
    float a6 = b6[t];
    for (int k = 0; k < 64; ++k) a6 = fmaf(h2[k], W6[k * 2 + t], a6);
    out[g * 2 + t] = a6;
  }
}

// ---------------- launcher ----------------
extern "C" void kernel_launch(void* const* d_in, const int* in_sizes, int n_in,
                              void* d_out, int out_size, void* d_ws, size_t ws_size,
                              hipStream_t stream)
{
  const float* x          = (const float*)d_in[0];
  const int*   edge_index = (const int*)d_in[1];
  const int*   batch      = (const int*)d_in[2];
  const int n  = in_sizes[0] / 128;            // 50000
  const int nE = in_sizes[1] / 2;              // 1600000
  const int* esrc = edge_index;
  const int* edst = edge_index + nE;
  const int n_graphs = out_size / 2;           // 512

  const float *Wl[3], *bl[3], *Wr[3], *br[3], *att[3], *bias[3];
  for (int l = 0; l < 3; ++l){
    Wl[l]   = (const float*)d_in[3 + 6 * l + 0];
    bl[l]   = (const float*)d_in[3 + 6 * l + 1];
    Wr[l]   = (const float*)d_in[3 + 6 * l + 2];
    br[l]   = (const float*)d_in[3 + 6 * l + 3];
    att[l]  = (const float*)d_in[3 + 6 * l + 4];
    bias[l] = (const float*)d_in[3 + 6 * l + 5];
  }
  const float* W4 = (const float*)d_in[21]; const float* b4 = (const float*)d_in[22];
  const float* W5 = (const float*)d_in[23]; const float* b5 = (const float*)d_in[24];
  const float* W6 = (const float*)d_in[25]; const float* b6 = (const float*)d_in[26];

  char* ws = (char*)d_ws;
  size_t off = 0;
  auto alloc = [&](size_t bytes) -> void* {
    void* p = ws + off;
    off = (off + bytes + 255) & ~(size_t)255;
    return p;
  };
  int*   row_off = (int*)  alloc((size_t)(n + 1) * sizeof(int));
  int*   deg     = (int*)  alloc((size_t)n * sizeof(int));
  int*   cursor  = (int*)  alloc((size_t)n * sizeof(int));
  int*   csr_src = (int*)  alloc((size_t)(nE + n) * sizeof(int));
  unsigned short* xlb16 = (unsigned short*)alloc((size_t)n * 128 * sizeof(unsigned short));
  float* xrb     = (float*)alloc((size_t)n * 128 * sizeof(float));
  float* hC      = (float*)alloc((size_t)n * 128 * sizeof(float));
  float* hD      = (float*)alloc((size_t)n * 128 * sizeof(float));
  (void)ws_size; (void)n_in;

  // CSR build
  hipMemsetAsync(deg, 0, (size_t)n * sizeof(int), stream);
  hist_kernel<<<(nE / 8 + 255) / 256, 256, 0, stream>>>(edst, deg, nE);
  scan_kernel<<<1, 1024, 0, stream>>>(deg, row_off, cursor, csr_src, n);
  scatter_kernel<<<(nE / 8 + 255) / 256, 256, 0, stream>>>(esrc, edst, cursor, csr_src, nE);

  const int gemm_tiles = (n + 127) / 128;
  const int attn_blocks = ((size_t)n * 64 + 255) / 256;

  // layer 1
  gemm_xlxr_kernel<<<dim3(gemm_tiles, 2), 512, 0, stream>>>(x, Wl[0], bl[0], Wr[0], br[0],
                                                            xlb16, xrb, n);
  edge_attn_kernel<<<attn_blocks, 256, 0, stream>>>(xlb16, xrb, row_off, csr_src,
                                                    att[0], bias[0], hC, n, 1);
  // layer 2
  gemm_xlxr_kernel<<<dim3(gemm_tiles, 2), 512, 0, stream>>>(hC, Wl[1], bl[1], Wr[1], br[1],
                                                            xlb16, xrb, n);
  edge_attn_kernel<<<attn_blocks, 256, 0, stream>>>(xlb16, xrb, row_off, csr_src,
                                                    att[1], bias[1], hD, n, 1);
  // layer 3
  gemm_xlxr_kernel<<<dim3(gemm_tiles, 2), 512, 0, stream>>>(hD, Wl[2], bl[2], Wr[2], br[2],
                                                            xlb16, xrb, n);
  edge_attn_kernel<<<attn_blocks, 256, 0, stream>>>(xlb16, xrb, row_off, csr_src,
                                                    att[2], bias[2], hC, n, 0);

  pool_mlp_kernel<<<n_graphs, 128, 0, stream>>>(hC, batch, n, W4, b4, W5, b5, W6, b6,
                                                (float*)d_out);
}

// Round 5
// 513.051 us; speedup vs baseline: 1.7920x; 1.5249x over previous
//
#include <hip/hip_runtime.h>
#include <hip/hip_bf16.h>
#include <math.h>

#define BK_SHIFT 7            // 128 nodes per bucket
#define BK_NODES 128

// ---------------- device helpers ----------------
__device__ __forceinline__ int dev_lower_bound(const int* __restrict__ a, int n, int v){
  int lo = 0, hi = n;
  while (lo < hi){ int mid = (lo + hi) >> 1; if (a[mid] < v) lo = mid + 1; else hi = mid; }
  return lo;
}

__device__ __forceinline__ float4 bf4_to_f4(ushort4 u){
  return make_float4(__uint_as_float((unsigned)u.x << 16),
                     __uint_as_float((unsigned)u.y << 16),
                     __uint_as_float((unsigned)u.z << 16),
                     __uint_as_float((unsigned)u.w << 16));
}

__device__ __forceinline__ unsigned short f_to_bf(float f){
  __hip_bfloat16 h = __float2bfloat16(f);      // RNE
  return *reinterpret_cast<unsigned short*>(&h);
}

// ================= bucketed CSR build =================
// P1: count edges per 128-node dst bucket (LDS hist -> few global atomics)
__global__ __launch_bounds__(256) void p1_bucket_count(const int* __restrict__ edst,
    int* __restrict__ bktTotal, int nE, int K){
  __shared__ int cnt[512];
  for (int k = threadIdx.x; k < K; k += 256) cnt[k] = 0;
  __syncthreads();
  int i = (blockIdx.x * 256 + threadIdx.x) * 8;
  if (i + 7 < nE){
    int4 a = *(const int4*)(edst + i);
    int4 b = *(const int4*)(edst + i + 4);
    atomicAdd(&cnt[a.x >> BK_SHIFT], 1); atomicAdd(&cnt[a.y >> BK_SHIFT], 1);
    atomicAdd(&cnt[a.z >> BK_SHIFT], 1); atomicAdd(&cnt[a.w >> BK_SHIFT], 1);
    atomicAdd(&cnt[b.x >> BK_SHIFT], 1); atomicAdd(&cnt[b.y >> BK_SHIFT], 1);
    atomicAdd(&cnt[b.z >> BK_SHIFT], 1); atomicAdd(&cnt[b.w >> BK_SHIFT], 1);
  } else {
    for (int j = i; j < nE; ++j) atomicAdd(&cnt[edst[j] >> BK_SHIFT], 1);
  }
  __syncthreads();
  for (int k = threadIdx.x; k < K; k += 256)
    if (cnt[k]) atomicAdd(&bktTotal[k], cnt[k]);
}

// P2: exclusive scan of bucket totals (K <= 512, one block)
__global__ __launch_bounds__(512) void p2_scan(const int* __restrict__ bktTotal,
    int* __restrict__ bktBase, int* __restrict__ bktCur,
    int* __restrict__ row_off, int K, int n, int nE){
  __shared__ int sh[512];
  int t = threadIdx.x;
  int v = (t < K) ? bktTotal[t] : 0;
  sh[t] = v;
  __syncthreads();
  for (int off = 1; off < 512; off <<= 1){
    int u = (t >= off) ? sh[t - off] : 0;
    __syncthreads();
    sh[t] += u;
    __syncthreads();
  }
  if (t < K){
    int excl = sh[t] - v;
    bktBase[t] = excl;
    bktCur[t]  = excl;
  }
  if (t == 0){
    bktBase[K] = nE;            // total real edges
    row_off[n] = nE + n;        // + self loops
  }
}

// P3: partition edges into bucket-grouped ebuf (src,dst) pairs
__global__ __launch_bounds__(256) void p3_partition(const int* __restrict__ esrc,
    const int* __restrict__ edst, int* __restrict__ bktCur,
    int2* __restrict__ ebuf, int nE, int K){
  __shared__ int cnt[512];
  __shared__ int base[512];
  for (int k = threadIdx.x; k < K; k += 256) cnt[k] = 0;
  __syncthreads();
  const int i0 = (blockIdx.x * 256 + threadIdx.x) * 8;
  const int i1 = min(i0 + 8, nE);
  int bkt[8];
  int sv[8], dv[8];
  int cnt_local = i1 - i0;
  for (int j = 0; j < cnt_local; ++j){
    sv[j] = esrc[i0 + j];
    dv[j] = edst[i0 + j];
    bkt[j] = dv[j] >> BK_SHIFT;
    atomicAdd(&cnt[bkt[j]], 1);
  }
  __syncthreads();
  for (int k = threadIdx.x; k < K; k += 256){
    int c = cnt[k];
    base[k] = c ? atomicAdd(&bktCur[k], c) : 0;
  }
  __syncthreads();
  for (int k = threadIdx.x; k < K; k += 256) cnt[k] = 0;
  __syncthreads();
  for (int j = 0; j < cnt_local; ++j){
    int r = atomicAdd(&cnt[bkt[j]], 1);
    ebuf[base[bkt[j]] + r] = make_int2(sv[j], dv[j]);
  }
}

// P4: one block per bucket: local hist -> local scan -> row_off slice ->
//     LDS-cursor scatter (no global atomics; writes confined to ~17KB window)
__global__ __launch_bounds__(256) void p4_build(const int2* __restrict__ ebuf,
    const int* __restrict__ bktBase, int* __restrict__ row_off,
    int* __restrict__ csr_src, int n){
  const int b = blockIdx.x;
  const int node0 = b << BK_SHIFT;
  const int nNodes = min(BK_NODES, n - node0);
  const int tid = threadIdx.x;
  __shared__ int ldeg[BK_NODES];
  __shared__ int lcur[BK_NODES];
  __shared__ int sc[BK_NODES];
  const int e0 = bktBase[b];
  const int e1 = bktBase[b + 1];
  if (tid < BK_NODES) ldeg[tid] = 0;
  __syncthreads();
  for (int i = e0 + tid; i < e1; i += 256)
    atomicAdd(&ldeg[ebuf[i].y - node0], 1);
  __syncthreads();
  // inclusive scan of (ldeg+1) over BK_NODES entries
  if (tid < BK_NODES) sc[tid] = (tid < nNodes) ? (ldeg[tid] + 1) : 0;
  __syncthreads();
  for (int off = 1; off < BK_NODES; off <<= 1){
    int u = 0;
    if (tid < BK_NODES && tid >= off) u = sc[tid - off];
    __syncthreads();
    if (tid < BK_NODES) sc[tid] += u;
    __syncthreads();
  }
  if (tid < nNodes){
    const int csr0 = e0 + node0;                 // edges before + self-loops before
    int ro = csr0 + sc[tid] - (ldeg[tid] + 1);   // exclusive
    row_off[node0 + tid] = ro;
    lcur[tid] = ro;
  }
  __syncthreads();
  for (int i = e0 + tid; i < e1; i += 256){
    int2 e = ebuf[i];
    int p = atomicAdd(&lcur[e.y - node0], 1);    // LDS atomic
    csr_src[p] = e.x;
  }
  __syncthreads();
  if (tid < nNodes)
    csr_src[lcur[tid]] = node0 + tid;            // self-loop at row end
}

// ---------------- fused xl/xr GEMM: tile 128x128, K=128 ----------------
// blockIdx.y==0: xl = X@Wl+bl written as BF16 ; blockIdx.y==1: xr fp32
__global__ __launch_bounds__(512) void gemm_xlxr_kernel(
    const float* __restrict__ X,
    const float* __restrict__ Wl, const float* __restrict__ bl,
    const float* __restrict__ Wr, const float* __restrict__ br,
    unsigned short* __restrict__ xl16, float* __restrict__ xr, int n)
{
  const bool left = (blockIdx.y == 0);
  const float* W = left ? Wl : Wr;
  const float* b = left ? bl : br;
  __shared__ float Ws[32][128];
  __shared__ float Xs[128][36];
  const int tid = threadIdx.x;
  const int row0 = blockIdx.x * 128;
  const int tc = tid & 31;
  const int tr = tid >> 5;
  float acc[8][4] = {};
  for (int kc = 0; kc < 128; kc += 32){
    for (int idx = tid; idx < 1024; idx += 512){
      int r = idx >> 5, c4 = idx & 31;
      *(float4*)(&Ws[r][c4 * 4]) = *(const float4*)(W + (size_t)(kc + r) * 128 + c4 * 4);
    }
    for (int idx = tid; idx < 1024; idx += 512){
      int r = idx >> 3, c4 = idx & 7;
      int grow = row0 + r;
      float4 v = make_float4(0.f, 0.f, 0.f, 0.f);
      if (grow < n) v = *(const float4*)(X + (size_t)grow * 128 + kc + c4 * 4);
      *(float4*)(&Xs[r][c4 * 4]) = v;
    }
    __syncthreads();
    #pragma unroll
    for (int k = 0; k < 32; ++k){
      float4 w = *(const float4*)(&Ws[k][tc * 4]);
      #pragma unroll
      for (int r = 0; r < 8; ++r){
        float xv = Xs[tr * 8 + r][k];
        acc[r][0] = fmaf(xv, w.x, acc[r][0]);
        acc[r][1] = fmaf(xv, w.y, acc[r][1]);
        acc[r][2] = fmaf(xv, w.z, acc[r][2]);
        acc[r][3] = fmaf(xv, w.w, acc[r][3]);
      }
    }
    __syncthreads();
  }
  float4 bv = *(const float4*)(b + tc * 4);
  #pragma unroll
  for (int r = 0; r < 8; ++r){
    int grow = row0 + tr * 8 + r;
    if (grow < n){
      float ox = acc[r][0] + bv.x, oy = acc[r][1] + bv.y;
      float oz = acc[r][2] + bv.z, ow = acc[r][3] + bv.w;
      if (left){
        ushort4 o;
        o.x = f_to_bf(ox); o.y = f_to_bf(oy); o.z = f_to_bf(oz); o.w = f_to_bf(ow);
        *(ushort4*)(xl16 + (size_t)grow * 128 + tc * 4) = o;
      } else {
        *(float4*)(xr + (size_t)grow * 128 + tc * 4) = make_float4(ox, oy, oz, ow);
      }
    }
  }
}

// ---------------- per-destination online-softmax attention ----------------
__global__ __launch_bounds__(256) void edge_attn_kernel(
    const unsigned short* __restrict__ xl16, const float* __restrict__ xr,
    const int* __restrict__ row_off, const int* __restrict__ csr_src,
    const float* __restrict__ att, const float* __restrict__ bias,
    float* __restrict__ out, int n, int do_relu)
{
  const int node = (blockIdx.x * blockDim.x + threadIdx.x) >> 6;
  if (node >= n) return;
  const int lane = threadIdx.x & 63;
  const int half = lane >> 5;
  const int f4 = (lane & 31) * 4;

  const float4 xrv  = *(const float4*)(xr + (size_t)node * 128 + f4);
  const float4 attv = *(const float4*)(att + f4);
  const int base = row_off[node];
  const int deg  = row_off[node + 1] - base;       // >= 1 (self-loop)
  const int iters = (deg + 3) >> 2;

  float m = -3.0e38f, s = 0.f;
  float ax = 0.f, ay = 0.f, az = 0.f, aw = 0.f;

  for (int it = 0; it < iters; ++it){
    const int e0 = it * 4 + half * 2;
    const int e1 = e0 + 1;
    const int c0 = min(e0, deg - 1);
    const int c1 = min(e1, deg - 1);
    const int s0 = csr_src[base + c0];
    const int s1 = csr_src[base + c1];
    const float4 x0 = bf4_to_f4(*(const ushort4*)(xl16 + (size_t)s0 * 128 + f4));
    const float4 x1 = bf4_to_f4(*(const ushort4*)(xl16 + (size_t)s1 * 128 + f4));

    float t, p0, p1;
    t = x0.x + xrv.x; t = fmaxf(t, 0.2f * t); p0 = t * attv.x;
    t = x0.y + xrv.y; t = fmaxf(t, 0.2f * t); p0 = fmaf(t, attv.y, p0);
    t = x0.z + xrv.z; t = fmaxf(t, 0.2f * t); p0 = fmaf(t, attv.z, p0);
    t = x0.w + xrv.w; t = fmaxf(t, 0.2f * t); p0 = fmaf(t, attv.w, p0);
    t = x1.x + xrv.x; t = fmaxf(t, 0.2f * t); p1 = t * attv.x;
    t = x1.y + xrv.y; t = fmaxf(t, 0.2f * t); p1 = fmaf(t, attv.y, p1);
    t = x1.z + xrv.z; t = fmaxf(t, 0.2f * t); p1 = fmaf(t, attv.z, p1);
    t = x1.w + xrv.w; t = fmaxf(t, 0.2f * t); p1 = fmaf(t, attv.w, p1);
    #pragma unroll
    for (int off = 1; off < 32; off <<= 1){
      p0 += __shfl_xor(p0, off);
      p1 += __shfl_xor(p1, off);
    }
    float mnew = fmaxf(fmaxf(m, p0), p1);
    float sc = __expf(m - mnew);
    float q0 = __expf(p0 - mnew);
    float q1 = __expf(p1 - mnew);
    q0 = (e0 < deg) ? q0 : 0.f;
    q1 = (e1 < deg) ? q1 : 0.f;
    s  = fmaf(s, sc, q0 + q1);
    ax = fmaf(ax, sc, fmaf(q0, x0.x, q1 * x1.x));
    ay = fmaf(ay, sc, fmaf(q0, x0.y, q1 * x1.y));
    az = fmaf(az, sc, fmaf(q0, x0.z, q1 * x1.z));
    aw = fmaf(aw, sc, fmaf(q0, x0.w, q1 * x1.w));
    m = mnew;
  }

  float mo = __shfl_xor(m, 32);
  float mm = fmaxf(m, mo);
  float sc = __expf(m - mm);
  s *= sc; ax *= sc; ay *= sc; az *= sc; aw *= sc;
  s  += __shfl_xor(s , 32);
  ax += __shfl_xor(ax, 32);
  ay += __shfl_xor(ay, 32);
  az += __shfl_xor(az, 32);
  aw += __shfl_xor(aw, 32);

  if (half == 0){
    const float inv = 1.0f / s;
    const float4 bv = *(const float4*)(bias + f4);
    float ox = fmaf(ax, inv, bv.x);
    float oy = fmaf(ay, inv, bv.y);
    float oz = fmaf(az, inv, bv.z);
    float ow = fmaf(aw, inv, bv.w);
    if (do_relu){
      ox = fmaxf(ox, 0.f); oy = fmaxf(oy, 0.f);
      oz = fmaxf(oz, 0.f); ow = fmaxf(ow, 0.f);
    }
    *(float4*)(out + (size_t)node * 128 + f4) = make_float4(ox, oy, oz, ow);
  }
}

// ---------------- mean-pool + MLP head ----------------
__global__ __launch_bounds__(128) void pool_mlp_kernel(
    const float* __restrict__ h, const int* __restrict__ batch, int n,
    const float* __restrict__ W4, const float* __restrict__ b4,
    const float* __restrict__ W5, const float* __restrict__ b5,
    const float* __restrict__ W6, const float* __restrict__ b6,
    float* __restrict__ out)
{
  int g = blockIdx.x;
  int t = threadIdx.x;
  __shared__ float gf[128];
  __shared__ float h1[128];
  __shared__ float h2[64];
  int lo = dev_lower_bound(batch, n, g);
  int hi = dev_lower_bound(batch, n, g + 1);
  float ssum = 0.f;
  for (int i = lo; i < hi; ++i) ssum += h[(size_t)i * 128 + t];
  float cnt = (float)(hi - lo);
  gf[t] = ssum / fmaxf(cnt, 1.0f);
  __syncthreads();
  float a = b4[t];
  for (int k = 0; k < 128; ++k) a = fmaf(gf[k], W4[k * 128 + t], a);
  h1[t] = 1.0f / (1.0f + __expf(-a));
  __syncthreads();
  if (t < 64){
    float a5 = b5[t];
    for (int k = 0; k < 128; ++k) a5 = fmaf(h1[k], W5[k * 64 + t], a5);
    h2[t] = 1.0f / (1.0f + __expf(-a5));
  }
  __syncthreads();
  if (t < 2){
    float a6 = b6[t];
    for (int k = 0; k < 64; ++k) a6 = fmaf(h2[k], W6[k * 2 + t], a6);
    out[g * 2 + t] = a6;
  }
}

// ---------------- launcher ----------------
extern "C" void kernel_launch(void* const* d_in, const int* in_sizes, int n_in,
                              void* d_out, int out_size, void* d_ws, size_t ws_size,
                              hipStream_t stream)
{
  const float* x          = (const float*)d_in[0];
  const int*   edge_index = (const int*)d_in[1];
  const int*   batch      = (const int*)d_in[2];
  const int n  = in_sizes[0] / 128;            // 50000
  const int nE = in_sizes[1] / 2;              // 1600000
  const int* esrc = edge_index;
  const int* edst = edge_index + nE;
  const int n_graphs = out_size / 2;           // 512
  const int K = (n + BK_NODES - 1) >> BK_SHIFT; // 391 buckets (<=512 for n<=65536)

  const float *Wl[3], *bl[3], *Wr[3], *br[3], *att[3], *bias[3];
  for (int l = 0; l < 3; ++l){
    Wl[l]   = (const float*)d_in[3 + 6 * l + 0];
    bl[l]   = (const float*)d_in[3 + 6 * l + 1];
    Wr[l]   = (const float*)d_in[3 + 6 * l + 2];
    br[l]   = (const float*)d_in[3 + 6 * l + 3];
    att[l]  = (const float*)d_in[3 + 6 * l + 4];
    bias[l] = (const float*)d_in[3 + 6 * l + 5];
  }
  const float* W4 = (const float*)d_in[21]; const float* b4 = (const float*)d_in[22];
  const float* W5 = (const float*)d_in[23]; const float* b5 = (const float*)d_in[24];
  const float* W6 = (const float*)d_in[25]; const float* b6 = (const float*)d_in[26];

  char* ws = (char*)d_ws;
  size_t off = 0;
  auto alloc = [&](size_t bytes) -> void* {
    void* p = ws + off;
    off = (off + bytes + 255) & ~(size_t)255;
    return p;
  };
  int*   row_off  = (int*)  alloc((size_t)(n + 1) * sizeof(int));
  int*   bktTotal = (int*)  alloc(512 * sizeof(int));
  int*   bktBase  = (int*)  alloc(513 * sizeof(int));
  int*   bktCur   = (int*)  alloc(512 * sizeof(int));
  int*   csr_src  = (int*)  alloc((size_t)(nE + n) * sizeof(int));
  int2*  ebuf     = (int2*) alloc((size_t)nE * sizeof(int2));
  unsigned short* xlb16 = (unsigned short*)alloc((size_t)n * 128 * sizeof(unsigned short));
  float* xrb      = (float*)alloc((size_t)n * 128 * sizeof(float));
  float* hC       = (float*)alloc((size_t)n * 128 * sizeof(float));
  (void)ws_size; (void)n_in;

  // ---- bucketed CSR build ----
  hipMemsetAsync(bktTotal, 0, 512 * sizeof(int), stream);
  const int eblocks = (nE + 2048 - 1) / 2048;      // 8 edges/thread, 256 thr
  p1_bucket_count<<<eblocks, 256, 0, stream>>>(edst, bktTotal, nE, K);
  p2_scan<<<1, 512, 0, stream>>>(bktTotal, bktBase, bktCur, row_off, K, n, nE);
  p3_partition<<<eblocks, 256, 0, stream>>>(esrc, edst, bktCur, ebuf, nE, K);
  p4_build<<<K, 256, 0, stream>>>(ebuf, bktBase, row_off, csr_src, n);

  const int gemm_tiles = (n + 127) / 128;
  const int attn_blocks = (int)(((size_t)n * 64 + 255) / 256);

  // layer 1
  gemm_xlxr_kernel<<<dim3(gemm_tiles, 2), 512, 0, stream>>>(x, Wl[0], bl[0], Wr[0], br[0],
                                                            xlb16, xrb, n);
  edge_attn_kernel<<<attn_blocks, 256, 0, stream>>>(xlb16, xrb, row_off, csr_src,
                                                    att[0], bias[0], hC, n, 1);
  // layer 2 (hC dead after gemm reads it -> attn may overwrite)
  gemm_xlxr_kernel<<<dim3(gemm_tiles, 2), 512, 0, stream>>>(hC, Wl[1], bl[1], Wr[1], br[1],
                                                            xlb16, xrb, n);
  edge_attn_kernel<<<attn_blocks, 256, 0, stream>>>(xlb16, xrb, row_off, csr_src,
                                                    att[1], bias[1], hC, n, 1);
  // layer 3
  gemm_xlxr_kernel<<<dim3(gemm_tiles, 2), 512, 0, stream>>>(hC, Wl[2], bl[2], Wr[2], br[2],
                                                            xlb16, xrb, n);
  edge_attn_kernel<<<attn_blocks, 256, 0, stream>>>(xlb16, xrb, row_off, csr_src,
                                                    att[2], bias[2], hC, n, 0);

  pool_mlp_kernel<<<n_graphs, 128, 0, stream>>>(hC, batch, n, W4, b4, W5, b5, W6, b6,
                                                (float*)d_out);
}